// Round 2
// baseline (1371.761 us; speedup 1.0000x reference)
//
#include <hip/hip_runtime.h>

// LowBitMLP on MI355X (gfx950).
// Memory plan (R1: ws cut 288MB -> 160MB after R0 abort = suspected ws overrun):
//   d_out (64MB, scratch until GEMM2):
//     [0,32M)   x_h : x cast to f16        (8192x2048)
//     [32M,64M) tw1 : ternary(w1) as f16   (8192x2048)
//   d_ws (160MB used):
//     [0,32M)   tw2 : ternary(w2) as f16   (2048x8192)
//     [32M,160M) h  : GEMM1 out f16, LN1+relu in place (8192x8192)
//   GEMM2 writes f32 directly to d_out (xh/tw1 dead by then);
//   final LN runs in place on d_out.
// GEMM kernel: 128x128 block tile, 4 waves (2x2 of 64x64 wave tiles),
// 16x16x32 f16 MFMA, BK=32, global_load_lds width=16 staging into a
// fragment-blocked LDS layout (each 16x32 fragment = contiguous 1KB =>
// conflict-free ds_read_b128 at lds offset lane*16; staging lds addr is
// wave-uniform base + lane*16, per the m104/m108 constraint).

#define THRESH 0.1f
#define LN_EPS 1e-5f

typedef _Float16 f16x8 __attribute__((ext_vector_type(8)));
typedef float f32x4 __attribute__((ext_vector_type(4)));

typedef __attribute__((address_space(3))) void lds_void;
typedef const __attribute__((address_space(1))) void glob_void;

__device__ __forceinline__ void gld16(const void* g, void* l) {
  __builtin_amdgcn_global_load_lds((glob_void*)g, (lds_void*)l, 16, 0, 0);
}

// ---------------- elementwise prep ----------------

__global__ __launch_bounds__(256) void cvt_x_f16(const float* __restrict__ x,
                                                 _Float16* __restrict__ y) {
  const long i = ((long)blockIdx.x * 256 + threadIdx.x) * 8;
  const float4 v0 = *(const float4*)(x + i);
  const float4 v1 = *(const float4*)(x + i + 4);
  const float a[8] = {v0.x, v0.y, v0.z, v0.w, v1.x, v1.y, v1.z, v1.w};
  f16x8 o;
#pragma unroll
  for (int e = 0; e < 8; ++e) o[e] = (_Float16)a[e];
  *(f16x8*)(y + i) = o;
}

__global__ __launch_bounds__(256) void quant_w(const float* __restrict__ w,
                                               _Float16* __restrict__ t) {
  const long i = ((long)blockIdx.x * 256 + threadIdx.x) * 8;
  const float4 v0 = *(const float4*)(w + i);
  const float4 v1 = *(const float4*)(w + i + 4);
  const float a[8] = {v0.x, v0.y, v0.z, v0.w, v1.x, v1.y, v1.z, v1.w};
  f16x8 o;
#pragma unroll
  for (int e = 0; e < 8; ++e) {
    const float q = (fabsf(a[e]) < THRESH) ? 0.f : (a[e] > 0.f ? 1.f : -1.f);
    o[e] = (_Float16)q;
  }
  *(f16x8*)(t + i) = o;
}

// ---------------- GEMM-BT: C = A(MxK) * B(NxK)^T, fused (acc+b)*s ----------------

template <bool OUT_F16>
__global__ __launch_bounds__(256) void gemm_bt(const _Float16* __restrict__ A,
                                               const _Float16* __restrict__ B,
                                               void* __restrict__ C,
                                               const float* __restrict__ bias,
                                               const float* __restrict__ scale,
                                               int N, int K) {
  // Fragment-blocked LDS: 8 fragment blocks (16 rows x 32 k) x 512 f16 each.
  __shared__ _Float16 sA[8 * 512];
  __shared__ _Float16 sB[8 * 512];

  const int tid = threadIdx.x;
  const long row0 = (long)blockIdx.y * 128;
  const long col0 = (long)blockIdx.x * 128;
  const int wave = tid >> 6, lane = tid & 63;
  const int wm = (wave & 1) * 4;   // m fragment-block base (0 or 4)
  const int wn = (wave >> 1) * 4;  // n fragment-block base
  const int qd = lane >> 4, l16 = lane & 15;

  // Staging: linear lds 16B-chunk index l (0..511) maps to
  // fragment block l>>6, k-oct (l>>4)&3, row l&15 of the 128x32 tile.
  const int l0 = tid, l1 = tid + 256;
  const _Float16* ga0 = A + ((row0 + ((l0 >> 6) << 4) + (l0 & 15)) * (long)K + (((l0 >> 4) & 3) << 3));
  const _Float16* ga1 = A + ((row0 + ((l1 >> 6) << 4) + (l1 & 15)) * (long)K + (((l1 >> 4) & 3) << 3));
  const _Float16* gb0 = B + ((col0 + ((l0 >> 6) << 4) + (l0 & 15)) * (long)K + (((l0 >> 4) & 3) << 3));
  const _Float16* gb1 = B + ((col0 + ((l1 >> 6) << 4) + (l1 & 15)) * (long)K + (((l1 >> 4) & 3) << 3));
  _Float16* la0 = sA + l0 * 8;
  _Float16* la1 = sA + l1 * 8;
  _Float16* lb0 = sB + l0 * 8;
  _Float16* lb1 = sB + l1 * 8;

  f32x4 acc[4][4] = {};

  for (int k0 = 0; k0 < K; k0 += 32) {
    __syncthreads();
    gld16(ga0 + k0, la0);
    gld16(ga1 + k0, la1);
    gld16(gb0 + k0, lb0);
    gld16(gb1 + k0, lb1);
    __syncthreads();  // drains vmcnt => LDS tiles complete

    f16x8 af[4], bf[4];
#pragma unroll
    for (int i = 0; i < 4; ++i) af[i] = *(const f16x8*)&sA[(wm + i) * 512 + lane * 8];
#pragma unroll
    for (int j = 0; j < 4; ++j) bf[j] = *(const f16x8*)&sB[(wn + j) * 512 + lane * 8];
#pragma unroll
    for (int i = 0; i < 4; ++i)
#pragma unroll
      for (int j = 0; j < 4; ++j)
        acc[i][j] = __builtin_amdgcn_mfma_f32_16x16x32_f16(af[i], bf[j], acc[i][j], 0, 0, 0);
  }

  // Epilogue: C/D layout col = lane&15, row = (lane>>4)*4 + reg.
#pragma unroll
  for (int j = 0; j < 4; ++j) {
    const long c = col0 + (wn + j) * 16 + l16;
    const float bb = bias[c];
    const float ss = scale[c];
#pragma unroll
    for (int i = 0; i < 4; ++i) {
      const long r = row0 + (wm + i) * 16 + qd * 4;
#pragma unroll
      for (int reg = 0; reg < 4; ++reg) {
        const float v = (acc[i][j][reg] + bb) * ss;
        if constexpr (OUT_F16)
          ((_Float16*)C)[(r + reg) * (long)N + c] = (_Float16)v;
        else
          ((float*)C)[(r + reg) * (long)N + c] = v;
      }
    }
  }
}

// ---------------- row LayerNorm kernels ----------------

// D = 8192, f16 in/out, LN*g+b then relu, in place. One block (256 thr) per row.
__global__ __launch_bounds__(256) void ln_relu_rows_f16(_Float16* __restrict__ h,
                                                        const float* __restrict__ g,
                                                        const float* __restrict__ b) {
  const int D = 8192;
  const long base = (long)blockIdx.x * D;
  const int tid = threadIdx.x;
  f16x8 v[4];
  float sum = 0.f, sq = 0.f;
#pragma unroll
  for (int c = 0; c < 4; ++c) {
    v[c] = *(const f16x8*)&h[base + c * 2048 + tid * 8];
#pragma unroll
    for (int e = 0; e < 8; ++e) {
      const float f = (float)v[c][e];
      sum += f;
      sq += f * f;
    }
  }
#pragma unroll
  for (int off = 32; off > 0; off >>= 1) {
    sum += __shfl_down(sum, off);
    sq += __shfl_down(sq, off);
  }
  __shared__ float rs[4], rq[4];
  const int wv = tid >> 6, ln = tid & 63;
  if (ln == 0) { rs[wv] = sum; rq[wv] = sq; }
  __syncthreads();
  sum = rs[0] + rs[1] + rs[2] + rs[3];
  sq = rq[0] + rq[1] + rq[2] + rq[3];
  const float mu = sum / D;
  const float rstd = rsqrtf(sq / D - mu * mu + LN_EPS);
#pragma unroll
  for (int c = 0; c < 4; ++c) {
    const int col = c * 2048 + tid * 8;
    f16x8 o;
#pragma unroll
    for (int e = 0; e < 8; ++e) {
      const float f = ((float)v[c][e] - mu) * rstd * g[col + e] + b[col + e];
      o[e] = (_Float16)fmaxf(f, 0.f);
    }
    *(f16x8*)&h[base + col] = o;
  }
}

// D = 2048, f32, LN*g+b IN PLACE on d_out. One block (256 thr) per row;
// each block reads its whole row into registers before any write => safe.
__global__ __launch_bounds__(256) void ln_rows_f32_inplace(float* __restrict__ io,
                                                           const float* __restrict__ g,
                                                           const float* __restrict__ b) {
  const int D = 2048;
  const long base = (long)blockIdx.x * D;
  const int tid = threadIdx.x;
  const float4 v0 = *(const float4*)&io[base + tid * 8];
  const float4 v1 = *(const float4*)&io[base + tid * 8 + 4];
  const float a[8] = {v0.x, v0.y, v0.z, v0.w, v1.x, v1.y, v1.z, v1.w};
  float sum = 0.f, sq = 0.f;
#pragma unroll
  for (int e = 0; e < 8; ++e) {
    sum += a[e];
    sq += a[e] * a[e];
  }
#pragma unroll
  for (int off = 32; off > 0; off >>= 1) {
    sum += __shfl_down(sum, off);
    sq += __shfl_down(sq, off);
  }
  __shared__ float rs[4], rq[4];
  const int wv = tid >> 6, ln = tid & 63;
  if (ln == 0) { rs[wv] = sum; rq[wv] = sq; }
  __syncthreads();
  sum = rs[0] + rs[1] + rs[2] + rs[3];
  sq = rq[0] + rq[1] + rq[2] + rq[3];
  const float mu = sum / D;
  const float rstd = rsqrtf(sq / D - mu * mu + LN_EPS);
  const int col = tid * 8;
  float o[8];
#pragma unroll
  for (int e = 0; e < 8; ++e) o[e] = (a[e] - mu) * rstd * g[col + e] + b[col + e];
  *(float4*)&io[base + col] = make_float4(o[0], o[1], o[2], o[3]);
  *(float4*)&io[base + col + 4] = make_float4(o[4], o[5], o[6], o[7]);
}

// ---------------- launch ----------------

extern "C" void kernel_launch(void* const* d_in, const int* in_sizes, int n_in,
                              void* d_out, int out_size, void* d_ws, size_t ws_size,
                              hipStream_t stream) {
  const float* x    = (const float*)d_in[0];
  const float* w1   = (const float*)d_in[1];
  const float* b1   = (const float*)d_in[2];
  const float* s1   = (const float*)d_in[3];
  const float* w2   = (const float*)d_in[4];
  const float* b2   = (const float*)d_in[5];
  const float* s2   = (const float*)d_in[6];
  const float* ln1g = (const float*)d_in[7];
  const float* ln1b = (const float*)d_in[8];
  const float* outg = (const float*)d_in[9];
  const float* outb = (const float*)d_in[10];

  const int N = 8192, D_IN = 2048, D_H = 8192, D_OUT = 2048;
  const size_t MB = 1024 * 1024;
  // Scratch phase-1 buffers live in d_out (64MB); dead before GEMM2 writes it.
  char* ob = (char*)d_out;
  _Float16* xh  = (_Float16*)(ob);            // 32MB
  _Float16* tw1 = (_Float16*)(ob + 32 * MB);  // 32MB
  // Persistent-through-GEMM2 buffers in d_ws (160MB used).
  char* ws = (char*)d_ws;
  _Float16* tw2 = (_Float16*)(ws);            // 32MB
  _Float16* h   = (_Float16*)(ws + 32 * MB);  // 128MB

  // elementwise prep: each block handles 2048 elems
  cvt_x_f16<<<(N * D_IN) / 2048, 256, 0, stream>>>(x, xh);
  quant_w<<<(D_H * D_IN) / 2048, 256, 0, stream>>>(w1, tw1);
  quant_w<<<(D_OUT * D_H) / 2048, 256, 0, stream>>>(w2, tw2);

  // layer 1: h = (x @ tw1^T + b1) * s1   -> f16
  gemm_bt<true><<<dim3(D_H / 128, N / 128), 256, 0, stream>>>(xh, tw1, h, b1, s1, D_H, D_IN);
  // LN + relu in place
  ln_relu_rows_f16<<<N, 256, 0, stream>>>(h, ln1g, ln1b);

  // layer 2: (h @ tw2^T + b2) * s2 -> f32, straight into d_out (xh/tw1 dead)
  gemm_bt<false><<<dim3(D_OUT / 128, N / 128), 256, 0, stream>>>(h, tw2, d_out, b2, s2, D_OUT, D_H);
  // final LN in place on d_out
  ln_rows_f32_inplace<<<N, 256, 0, stream>>>((float*)d_out, outg, outb);
}

// Round 3
// 1323.375 us; speedup vs baseline: 1.0366x; 1.0366x over previous
//
#include <hip/hip_runtime.h>

// LowBitMLP on MI355X (gfx950).
// R2: LDS double-buffered GEMM K-loop (1 barrier/iter, next-iter
// global_load_lds issued before current compute) to hide the ~400cyc
// L2/LLC load latency that the R1 two-barrier loop exposed every iter
// (R1 PMC: MfmaUtil 18%, VALUBusy 29%, HBM 8% => latency-bound).
//
// Memory plan:
//   d_out (64MB, scratch until GEMM2):
//     [0,32M)   x_h : x cast to f16        (8192x2048)
//     [32M,64M) tw1 : ternary(w1) as f16   (8192x2048)
//   d_ws (160MB used):
//     [0,32M)   tw2 : ternary(w2) as f16   (2048x8192)
//     [32M,160M) h  : GEMM1 out f16, LN1+relu in place (8192x8192)
//   GEMM2 writes f32 directly to d_out (xh/tw1 dead by then);
//   final LN runs in place on d_out.

#define THRESH 0.1f
#define LN_EPS 1e-5f

typedef _Float16 f16x8 __attribute__((ext_vector_type(8)));
typedef float f32x4 __attribute__((ext_vector_type(4)));

typedef __attribute__((address_space(3))) void lds_void;
typedef const __attribute__((address_space(1))) void glob_void;

__device__ __forceinline__ void gld16(const void* g, void* l) {
  __builtin_amdgcn_global_load_lds((glob_void*)g, (lds_void*)l, 16, 0, 0);
}

// ---------------- elementwise prep ----------------

__global__ __launch_bounds__(256) void cvt_x_f16(const float* __restrict__ x,
                                                 _Float16* __restrict__ y) {
  const long i = ((long)blockIdx.x * 256 + threadIdx.x) * 8;
  const float4 v0 = *(const float4*)(x + i);
  const float4 v1 = *(const float4*)(x + i + 4);
  const float a[8] = {v0.x, v0.y, v0.z, v0.w, v1.x, v1.y, v1.z, v1.w};
  f16x8 o;
#pragma unroll
  for (int e = 0; e < 8; ++e) o[e] = (_Float16)a[e];
  *(f16x8*)(y + i) = o;
}

__global__ __launch_bounds__(256) void quant_w(const float* __restrict__ w,
                                               _Float16* __restrict__ t) {
  const long i = ((long)blockIdx.x * 256 + threadIdx.x) * 8;
  const float4 v0 = *(const float4*)(w + i);
  const float4 v1 = *(const float4*)(w + i + 4);
  const float a[8] = {v0.x, v0.y, v0.z, v0.w, v1.x, v1.y, v1.z, v1.w};
  f16x8 o;
#pragma unroll
  for (int e = 0; e < 8; ++e) {
    const float q = (fabsf(a[e]) < THRESH) ? 0.f : (a[e] > 0.f ? 1.f : -1.f);
    o[e] = (_Float16)q;
  }
  *(f16x8*)(t + i) = o;
}

// ---------------- GEMM-BT: C = A(MxK) * B(NxK)^T, fused (acc+b)*s ----------------
// 128x128 block tile, 4 waves (2x2 of 64x64 wave tiles), 16x16x32 f16 MFMA,
// BK=32, double-buffered LDS. Fragment-blocked LDS layout: each 16x32
// fragment contiguous 1KB => conflict-free ds_read_b128; staging lds addr is
// wave-uniform base + lane*16 (m104/m108 constraint satisfied).

template <bool OUT_F16>
__global__ __launch_bounds__(256) void gemm_bt(const _Float16* __restrict__ A,
                                               const _Float16* __restrict__ B,
                                               void* __restrict__ C,
                                               const float* __restrict__ bias,
                                               const float* __restrict__ scale,
                                               int N, int K) {
  __shared__ _Float16 sA[2][8 * 512];
  __shared__ _Float16 sB[2][8 * 512];

  const int tid = threadIdx.x;
  const long row0 = (long)blockIdx.y * 128;
  const long col0 = (long)blockIdx.x * 128;
  const int wave = tid >> 6, lane = tid & 63;
  const int wm = (wave & 1) * 4;   // m fragment-block base (0 or 4)
  const int wn = (wave >> 1) * 4;  // n fragment-block base
  const int qd = lane >> 4, l16 = lane & 15;

  // Staging: linear lds 16B-chunk index l (0..511) maps to
  // fragment block l>>6, k-oct (l>>4)&3, row l&15 of the 128x32 tile.
  const int l0 = tid, l1 = tid + 256;
  const _Float16* ga0 = A + ((row0 + ((l0 >> 6) << 4) + (l0 & 15)) * (long)K + (((l0 >> 4) & 3) << 3));
  const _Float16* ga1 = A + ((row0 + ((l1 >> 6) << 4) + (l1 & 15)) * (long)K + (((l1 >> 4) & 3) << 3));
  const _Float16* gb0 = B + ((col0 + ((l0 >> 6) << 4) + (l0 & 15)) * (long)K + (((l0 >> 4) & 3) << 3));
  const _Float16* gb1 = B + ((col0 + ((l1 >> 6) << 4) + (l1 & 15)) * (long)K + (((l1 >> 4) & 3) << 3));

  f32x4 acc[4][4] = {};

  // Prologue: stage k-tile 0 into buffer 0.
  gld16(ga0, sA[0] + l0 * 8);
  gld16(ga1, sA[0] + l1 * 8);
  gld16(gb0, sB[0] + l0 * 8);
  gld16(gb1, sB[0] + l1 * 8);

  const int nIter = K >> 5;
  for (int it = 0; it < nIter; ++it) {
    const int cur = it & 1;
    // Barrier: compiler-inserted s_waitcnt vmcnt(0) drains buf[cur] loads
    // (issued one full compute-phase ago) and guarantees all waves are done
    // reading buf[cur^1] before we overwrite it below.
    __syncthreads();
    if (it + 1 < nIter) {
      const int kn = (it + 1) << 5;
      const int nx = cur ^ 1;
      gld16(ga0 + kn, sA[nx] + l0 * 8);
      gld16(ga1 + kn, sA[nx] + l1 * 8);
      gld16(gb0 + kn, sB[nx] + l0 * 8);
      gld16(gb1 + kn, sB[nx] + l1 * 8);
    }

    f16x8 af[4], bf[4];
#pragma unroll
    for (int i = 0; i < 4; ++i) af[i] = *(const f16x8*)&sA[cur][(wm + i) * 512 + lane * 8];
#pragma unroll
    for (int j = 0; j < 4; ++j) bf[j] = *(const f16x8*)&sB[cur][(wn + j) * 512 + lane * 8];
#pragma unroll
    for (int i = 0; i < 4; ++i)
#pragma unroll
      for (int j = 0; j < 4; ++j)
        acc[i][j] = __builtin_amdgcn_mfma_f32_16x16x32_f16(af[i], bf[j], acc[i][j], 0, 0, 0);
  }

  // Epilogue: C/D layout col = lane&15, row = (lane>>4)*4 + reg.
#pragma unroll
  for (int j = 0; j < 4; ++j) {
    const long c = col0 + (wn + j) * 16 + l16;
    const float bb = bias[c];
    const float ss = scale[c];
#pragma unroll
    for (int i = 0; i < 4; ++i) {
      const long r = row0 + (wm + i) * 16 + qd * 4;
#pragma unroll
      for (int reg = 0; reg < 4; ++reg) {
        const float v = (acc[i][j][reg] + bb) * ss;
        if constexpr (OUT_F16)
          ((_Float16*)C)[(r + reg) * (long)N + c] = (_Float16)v;
        else
          ((float*)C)[(r + reg) * (long)N + c] = v;
      }
    }
  }
}

// ---------------- row LayerNorm kernels ----------------

// D = 8192, f16 in/out, LN*g+b then relu, in place. One block (256 thr) per row.
__global__ __launch_bounds__(256) void ln_relu_rows_f16(_Float16* __restrict__ h,
                                                        const float* __restrict__ g,
                                                        const float* __restrict__ b) {
  const int D = 8192;
  const long base = (long)blockIdx.x * D;
  const int tid = threadIdx.x;
  f16x8 v[4];
  float sum = 0.f, sq = 0.f;
#pragma unroll
  for (int c = 0; c < 4; ++c) {
    v[c] = *(const f16x8*)&h[base + c * 2048 + tid * 8];
#pragma unroll
    for (int e = 0; e < 8; ++e) {
      const float f = (float)v[c][e];
      sum += f;
      sq += f * f;
    }
  }
#pragma unroll
  for (int off = 32; off > 0; off >>= 1) {
    sum += __shfl_down(sum, off);
    sq += __shfl_down(sq, off);
  }
  __shared__ float rs[4], rq[4];
  const int wv = tid >> 6, ln = tid & 63;
  if (ln == 0) { rs[wv] = sum; rq[wv] = sq; }
  __syncthreads();
  sum = rs[0] + rs[1] + rs[2] + rs[3];
  sq = rq[0] + rq[1] + rq[2] + rq[3];
  const float mu = sum / D;
  const float rstd = rsqrtf(sq / D - mu * mu + LN_EPS);
#pragma unroll
  for (int c = 0; c < 4; ++c) {
    const int col = c * 2048 + tid * 8;
    f16x8 o;
#pragma unroll
    for (int e = 0; e < 8; ++e) {
      const float f = ((float)v[c][e] - mu) * rstd * g[col + e] + b[col + e];
      o[e] = (_Float16)fmaxf(f, 0.f);
    }
    *(f16x8*)&h[base + col] = o;
  }
}

// D = 2048, f32, LN*g+b IN PLACE on d_out. One block (256 thr) per row;
// each block reads its whole row into registers before any write => safe.
__global__ __launch_bounds__(256) void ln_rows_f32_inplace(float* __restrict__ io,
                                                           const float* __restrict__ g,
                                                           const float* __restrict__ b) {
  const int D = 2048;
  const long base = (long)blockIdx.x * D;
  const int tid = threadIdx.x;
  const float4 v0 = *(const float4*)&io[base + tid * 8];
  const float4 v1 = *(const float4*)&io[base + tid * 8 + 4];
  const float a[8] = {v0.x, v0.y, v0.z, v0.w, v1.x, v1.y, v1.z, v1.w};
  float sum = 0.f, sq = 0.f;
#pragma unroll
  for (int e = 0; e < 8; ++e) {
    sum += a[e];
    sq += a[e] * a[e];
  }
#pragma unroll
  for (int off = 32; off > 0; off >>= 1) {
    sum += __shfl_down(sum, off);
    sq += __shfl_down(sq, off);
  }
  __shared__ float rs[4], rq[4];
  const int wv = tid >> 6, ln = tid & 63;
  if (ln == 0) { rs[wv] = sum; rq[wv] = sq; }
  __syncthreads();
  sum = rs[0] + rs[1] + rs[2] + rs[3];
  sq = rq[0] + rq[1] + rq[2] + rq[3];
  const float mu = sum / D;
  const float rstd = rsqrtf(sq / D - mu * mu + LN_EPS);
  const int col = tid * 8;
  float o[8];
#pragma unroll
  for (int e = 0; e < 8; ++e) o[e] = (a[e] - mu) * rstd * g[col + e] + b[col + e];
  *(float4*)&io[base + col] = make_float4(o[0], o[1], o[2], o[3]);
  *(float4*)&io[base + col + 4] = make_float4(o[4], o[5], o[6], o[7]);
}

// ---------------- launch ----------------

extern "C" void kernel_launch(void* const* d_in, const int* in_sizes, int n_in,
                              void* d_out, int out_size, void* d_ws, size_t ws_size,
                              hipStream_t stream) {
  const float* x    = (const float*)d_in[0];
  const float* w1   = (const float*)d_in[1];
  const float* b1   = (const float*)d_in[2];
  const float* s1   = (const float*)d_in[3];
  const float* w2   = (const float*)d_in[4];
  const float* b2   = (const float*)d_in[5];
  const float* s2   = (const float*)d_in[6];
  const float* ln1g = (const float*)d_in[7];
  const float* ln1b = (const float*)d_in[8];
  const float* outg = (const float*)d_in[9];
  const float* outb = (const float*)d_in[10];

  const int N = 8192, D_IN = 2048, D_H = 8192, D_OUT = 2048;
  const size_t MB = 1024 * 1024;
  // Scratch phase-1 buffers live in d_out (64MB); dead before GEMM2 writes it.
  char* ob = (char*)d_out;
  _Float16* xh  = (_Float16*)(ob);            // 32MB
  _Float16* tw1 = (_Float16*)(ob + 32 * MB);  // 32MB
  // Persistent-through-GEMM2 buffers in d_ws (160MB used).
  char* ws = (char*)d_ws;
  _Float16* tw2 = (_Float16*)(ws);            // 32MB
  _Float16* h   = (_Float16*)(ws + 32 * MB);  // 128MB

  // elementwise prep: each block handles 2048 elems
  cvt_x_f16<<<(N * D_IN) / 2048, 256, 0, stream>>>(x, xh);
  quant_w<<<(D_H * D_IN) / 2048, 256, 0, stream>>>(w1, tw1);
  quant_w<<<(D_OUT * D_H) / 2048, 256, 0, stream>>>(w2, tw2);

  // layer 1: h = (x @ tw1^T + b1) * s1   -> f16
  gemm_bt<true><<<dim3(D_H / 128, N / 128), 256, 0, stream>>>(xh, tw1, h, b1, s1, D_H, D_IN);
  // LN + relu in place
  ln_relu_rows_f16<<<N, 256, 0, stream>>>(h, ln1g, ln1b);

  // layer 2: (h @ tw2^T + b2) * s2 -> f32, straight into d_out (xh/tw1 dead)
  gemm_bt<false><<<dim3(D_OUT / 128, N / 128), 256, 0, stream>>>(h, tw2, d_out, b2, s2, D_OUT, D_H);
  // final LN in place on d_out
  ln_rows_f32_inplace<<<N, 256, 0, stream>>>((float*)d_out, outg, outb);
}